// Round 8
// baseline (114.047 us; speedup 1.0000x reference)
//
#include <hip/hip_runtime.h>

#define BATCH  2
#define SEQ    2048
#define DMODEL 1024
#define NHEAD  16
#define HD     64
#define BH     (BATCH * NHEAD)

typedef __attribute__((ext_vector_type(8))) short s8v;   // 8 bf16 = 4 VGPRs (MFMA A/B frag)
typedef __attribute__((ext_vector_type(4))) float f4v;   // MFMA C/D frag

__device__ inline unsigned short bf16_rne(float f) {
    unsigned u = __builtin_bit_cast(unsigned, f);
    u += 0x7FFFu + ((u >> 16) & 1u);
    return (unsigned short)(u >> 16);
}

// pack two f32 -> u32 of 2 bf16 (RNE via bit-trick; trivially copyable types)
__device__ __forceinline__ unsigned pk_bf16(float lo, float hi) {
    return (unsigned)bf16_rne(lo) | ((unsigned)bf16_rne(hi) << 16);
}

// ---------------------------------------------------------------------------
// Prep v2: x fp32 -> xb bf16 (same layout) and xbT bf16 [bh][d][s].
// grid 2048 = BH * SEQ/32, block 256. One 32(s) x 64(d) tile per block.
// [verbatim round-6, verified passing]
// ---------------------------------------------------------------------------
__global__ __launch_bounds__(256) void prep_kernel(const float* __restrict__ x,
                                                   unsigned short* __restrict__ xb,
                                                   unsigned short* __restrict__ xbT) {
    __shared__ unsigned short tile[32 * 66];   // stride 66 u16: avoids pow-2 conflicts
    const int id = blockIdx.x;
    const int bh = id & (BH - 1);
    const int st = id >> 5;                    // s-tile 0..63
    const int b = bh >> 4, h = bh & (NHEAD - 1);
    const int s0 = st * 32;
    const int tid = threadIdx.x;
    const int c4 = tid & 15, r16 = tid >> 4;

#pragma unroll
    for (int p = 0; p < 2; ++p) {
        const int sl = p * 16 + r16;
        const size_t off = (size_t)(b * SEQ + s0 + sl) * DMODEL + h * HD + c4 * 4;
        float4 v = *(const float4*)(x + off);
        ushort4 o;
        o.x = bf16_rne(v.x); o.y = bf16_rne(v.y);
        o.z = bf16_rne(v.z); o.w = bf16_rne(v.w);
        *(ushort4*)(xb + off) = o;
        unsigned short* t = tile + sl * 66 + c4 * 4;
        t[0] = o.x; t[1] = o.y; t[2] = o.z; t[3] = o.w;
    }
    __syncthreads();
    {
        const int d = tid >> 2;                // 0..63
        const int sb = (tid & 3) * 8;          // s-chunk 0,8,16,24
        s8v o;
#pragma unroll
        for (int j = 0; j < 8; ++j)
            o[j] = (short)tile[(sb + j) * 66 + d];
        *(s8v*)(xbT + (size_t)(bh * HD + d) * SEQ + s0 + sb) = o;
    }
}

// ---------------------------------------------------------------------------
// Stage one 64x64 K tile + 64x64 V^T tile into LDS buffer at bufoff.
// Waves 0,1: K rows (XOR-swizzled d-chunks). Waves 2,3: V^T rows (swizzled k).
// 4 x global_load_lds(16B) per wave.  [verbatim round-1, verified passing]
// ---------------------------------------------------------------------------
__device__ __forceinline__ void stage_tile(const unsigned short* __restrict__ xbh,
                                           const unsigned short* __restrict__ xTh,
                                           char* lds, int bufoff, int k0,
                                           int w, int sr, int sc) {
    if (w < 2) {
#pragma unroll
        for (int i = 0; i < 4; ++i) {
            const int r = w * 32 + i * 8 + sr;
            const unsigned short* gsrc =
                xbh + (size_t)(k0 + r) * DMODEL + ((sc ^ (r & 7)) * 8);
            const int loff = __builtin_amdgcn_readfirstlane(bufoff + (w * 32 + i * 8) * 128);
            __builtin_amdgcn_global_load_lds(
                (const __attribute__((address_space(1))) void*)gsrc,
                (__attribute__((address_space(3))) void*)(lds + loff), 16, 0, 0);
        }
    } else {
#pragma unroll
        for (int i = 0; i < 4; ++i) {
            const int d = (w - 2) * 32 + i * 8 + sr;
            const unsigned short* gsrc =
                xTh + (size_t)d * SEQ + k0 + ((sc ^ (d & 7)) * 8);
            const int loff =
                __builtin_amdgcn_readfirstlane(bufoff + 8192 + ((w - 2) * 32 + i * 8) * 128);
            __builtin_amdgcn_global_load_lds(
                (const __attribute__((address_space(1))) void*)gsrc,
                (__attribute__((address_space(3))) void*)(lds + loff), 16, 0, 0);
        }
    }
}

// ---------------------------------------------------------------------------
// Flash attention, bf16 MFMA 16x16x32, swapped QK^T (round-6 inner loop).
// QBLK=128: each wave owns TWO 16-row q-subtiles (A: rows qb+w*16+n, B: +64).
// K-frags and V-frags are read from LDS ONCE and feed both subtiles' MFMAs —
// removes the 4x-redundant LDS reads that saturated the LDS pipe (round-7
// evidence: occupancy raise gained ~0 -> CU-throughput bound).
// LDS 48KB: dbuf 2x16K (K|V^T, unchanged) + P scratch 4 waves x 4K (A|B).
// Schedule: grid 768 = 3 blocks/CU (b,b,a) triples, constant 34 iters/CU:
//   slot0/1: equal-length k-halves (twins) of tile qt'=15-i  -> partial
//   slot2:   whole short tile qt'=i                          -> direct out
// (slot = id>>8, c = id&255, bh = c&31, i = c>>5; ids c,c+256,c+512 land on
// one CU under round-robin dispatch — same assumption round-6 validated.)
// Causal mask via ql_eff in {63, w*16+n, -1} (full / diag / dead k-tile).
// ---------------------------------------------------------------------------
__global__ __launch_bounds__(256, 3) void flash_kernel(const unsigned short* __restrict__ xb,
                                                       const unsigned short* __restrict__ xbT,
                                                       float* __restrict__ out,
                                                       float* __restrict__ oPart,
                                                       float* __restrict__ lPart) {
    __shared__ __align__(16) char lds[49152];

    const int id = blockIdx.x;
    const int slot = id >> 8;                  // 0,1,2
    const int c = id & 255;
    const int bh = c & (BH - 1);
    const int i = c >> 5;                      // 0..7
    int qtp, kt0, ktEnd, half;
    bool partial;
    if (slot == 0) {        // lo twin of split tile (len 16-i)
        qtp = 15 - i; kt0 = 0;       ktEnd = qtp;         partial = true;  half = 0;
    } else if (slot == 1) { // hi twin of split tile (len 16-i)
        qtp = 15 - i; kt0 = qtp + 1; ktEnd = 2 * qtp + 1; partial = true;  half = 1;
    } else {                // whole short tile (len 2i+2)
        qtp = i;      kt0 = 0;       ktEnd = 2 * qtp + 1; partial = false; half = 0;
    }
    const int b = bh >> 4, h = bh & (NHEAD - 1);
    const int tid = threadIdx.x;
    const int w = tid >> 6;                            // wave 0..3
    const int lane = tid & 63;
    const int n = lane & 15;                           // MFMA m/n index
    const int g = lane >> 4;                           // MFMA quad
    const int qbase = qtp * 128;
    const int diagA = 2 * qtp;                         // diag k-tile, subtile A

    const unsigned short* xbh = xb + (size_t)b * SEQ * DMODEL + h * HD;
    const unsigned short* xTh = xbT + (size_t)bh * HD * SEQ;

    // Q fragments for both subtiles (B-operand in swapped QK^T)
    const int qrowA = qbase + w * 16 + n;
    const s8v qfA0 = *(const s8v*)(xbh + (size_t)qrowA * DMODEL + g * 8);
    const s8v qfA1 = *(const s8v*)(xbh + (size_t)qrowA * DMODEL + 32 + g * 8);
    const s8v qfB0 = *(const s8v*)(xbh + (size_t)(qrowA + 64) * DMODEL + g * 8);
    const s8v qfB1 = *(const s8v*)(xbh + (size_t)(qrowA + 64) * DMODEL + 32 + g * 8);

    // B-frag LDS byte offsets (round-6 formulas, verified)
    int roff0[4], roff1[4];
#pragma unroll
    for (int t = 0; t < 4; ++t) {
        roff0[t] = (t * 16 + n) * 128 + ((g ^ (n & 7)) * 16);
        roff1[t] = (t * 16 + n) * 128 + (((4 + g) ^ (n & 7)) * 16);
    }

    f4v oA0 = {0.f, 0.f, 0.f, 0.f}, oA1 = oA0, oA2 = oA0, oA3 = oA0;
    f4v oB0 = oA0, oB1 = oA0, oB2 = oA0, oB3 = oA0;
    float lsumA = 0.0f, lsumB = 0.0f;
    char* const Pbase = lds + 32768 + w * 4096;        // [A 2K | B 2K]

    char* wrP[4];
#pragma unroll
    for (int t = 0; t < 4; ++t)
        wrP[t] = Pbase + (t >> 1) * 1024 + n * 64 +
                 ((((t & 1) * 2 + (g >> 1)) ^ (n & 3)) * 16) + (g & 1) * 8;
    const char* rdP = Pbase + n * 64 + ((g ^ (n & 3)) * 16);

    const int sr = lane >> 3;
    const int sc = lane & 7;

    // prologue: prefetch first tile; buffer parity is absolute (kt&1)
    stage_tile(xbh, xTh, lds, (kt0 & 1) << 14, kt0 * 64, w, sr, sc);

    for (int kt = kt0; kt <= ktEnd; ++kt) {
        char* const buf = lds + ((kt & 1) << 14);
        __syncthreads();   // drains this tile's loads; buf^1 free for restage
        if (kt < ktEnd)
            stage_tile(xbh, xTh, lds, ((kt & 1) ^ 1) << 14, (kt + 1) * 64, w, sr, sc);

        // per-subtile causal bound: full tile -> 63, diag -> w*16+n, dead -> -1
        const int wn = w * 16 + n;
        const int qlA = (kt < diagA) ? 63 : ((kt == diagA) ? wn : -1);
        const int qlB = (kt < diagA + 1) ? 63 : wn;    // kt never exceeds diagB

        // ---- QK^T (A=K, B=Q) + softmax(no-max) + packed P scatter, both subs ----
#pragma unroll
        for (int t = 0; t < 4; ++t) {
            const s8v kb0 = *(const s8v*)(buf + roff0[t]);
            const s8v kb1 = *(const s8v*)(buf + roff1[t]);
            f4v cA = {0.f, 0.f, 0.f, 0.f}, cB = cA;
            __builtin_amdgcn_s_setprio(1);
            cA = __builtin_amdgcn_mfma_f32_16x16x32_bf16(kb0, qfA0, cA, 0, 0, 0);
            cA = __builtin_amdgcn_mfma_f32_16x16x32_bf16(kb1, qfA1, cA, 0, 0, 0);
            cB = __builtin_amdgcn_mfma_f32_16x16x32_bf16(kb0, qfB0, cB, 0, 0, 0);
            cB = __builtin_amdgcn_mfma_f32_16x16x32_bf16(kb1, qfB1, cB, 0, 0, 0);
            __builtin_amdgcn_s_setprio(0);
            const int kl = t * 16 + g * 4;
            float pA[4], pB[4];
#pragma unroll
            for (int r = 0; r < 4; ++r) {
                float a = __builtin_amdgcn_exp2f(cA[r] * 0.18033688011112042f);
                float bb = __builtin_amdgcn_exp2f(cB[r] * 0.18033688011112042f);
                pA[r] = (kl + r <= qlA) ? a : 0.0f;
                pB[r] = (kl + r <= qlB) ? bb : 0.0f;
            }
            lsumA += (pA[0] + pA[1]) + (pA[2] + pA[3]);
            lsumB += (pB[0] + pB[1]) + (pB[2] + pB[3]);
            uint2 uA, uB;
            uA.x = pk_bf16(pA[0], pA[1]); uA.y = pk_bf16(pA[2], pA[3]);
            uB.x = pk_bf16(pB[0], pB[1]); uB.y = pk_bf16(pB[2], pB[3]);
            *(uint2*)(wrP[t]) = uA;            // ds_write_b64
            *(uint2*)(wrP[t] + 2048) = uB;
        }

        // ---- PV: V-frags read ONCE, feed both subtiles ----
        const s8v paA0 = *(const s8v*)(rdP);
        const s8v paA1 = *(const s8v*)(rdP + 1024);
        const s8v paB0 = *(const s8v*)(rdP + 2048);
        const s8v paB1 = *(const s8v*)(rdP + 3072);
        const char* kColB = buf + 8192;
        {
            s8v vb;
            __builtin_amdgcn_s_setprio(1);
            vb = *(const s8v*)(kColB + roff0[0]);
            oA0 = __builtin_amdgcn_mfma_f32_16x16x32_bf16(paA0, vb, oA0, 0, 0, 0);
            oB0 = __builtin_amdgcn_mfma_f32_16x16x32_bf16(paB0, vb, oB0, 0, 0, 0);
            vb = *(const s8v*)(kColB + roff1[0]);
            oA0 = __builtin_amdgcn_mfma_f32_16x16x32_bf16(paA1, vb, oA0, 0, 0, 0);
            oB0 = __builtin_amdgcn_mfma_f32_16x16x32_bf16(paB1, vb, oB0, 0, 0, 0);
            vb = *(const s8v*)(kColB + roff0[1]);
            oA1 = __builtin_amdgcn_mfma_f32_16x16x32_bf16(paA0, vb, oA1, 0, 0, 0);
            oB1 = __builtin_amdgcn_mfma_f32_16x16x32_bf16(paB0, vb, oB1, 0, 0, 0);
            vb = *(const s8v*)(kColB + roff1[1]);
            oA1 = __builtin_amdgcn_mfma_f32_16x16x32_bf16(paA1, vb, oA1, 0, 0, 0);
            oB1 = __builtin_amdgcn_mfma_f32_16x16x32_bf16(paB1, vb, oB1, 0, 0, 0);
            vb = *(const s8v*)(kColB + roff0[2]);
            oA2 = __builtin_amdgcn_mfma_f32_16x16x32_bf16(paA0, vb, oA2, 0, 0, 0);
            oB2 = __builtin_amdgcn_mfma_f32_16x16x32_bf16(paB0, vb, oB2, 0, 0, 0);
            vb = *(const s8v*)(kColB + roff1[2]);
            oA2 = __builtin_amdgcn_mfma_f32_16x16x32_bf16(paA1, vb, oA2, 0, 0, 0);
            oB2 = __builtin_amdgcn_mfma_f32_16x16x32_bf16(paB1, vb, oB2, 0, 0, 0);
            vb = *(const s8v*)(kColB + roff0[3]);
            oA3 = __builtin_amdgcn_mfma_f32_16x16x32_bf16(paA0, vb, oA3, 0, 0, 0);
            oB3 = __builtin_amdgcn_mfma_f32_16x16x32_bf16(paB0, vb, oB3, 0, 0, 0);
            vb = *(const s8v*)(kColB + roff1[3]);
            oA3 = __builtin_amdgcn_mfma_f32_16x16x32_bf16(paA1, vb, oA3, 0, 0, 0);
            oB3 = __builtin_amdgcn_mfma_f32_16x16x32_bf16(paB1, vb, oB3, 0, 0, 0);
            __builtin_amdgcn_s_setprio(0);
        }
    }

    // ---- epilogue ----
    lsumA += __shfl_xor(lsumA, 16, 64);
    lsumA += __shfl_xor(lsumA, 32, 64);
    lsumB += __shfl_xor(lsumB, 16, 64);
    lsumB += __shfl_xor(lsumB, 32, 64);

    if (!partial) {
        f4v invA, invB;
#pragma unroll
        for (int r = 0; r < 4; ++r) {
            invA[r] = 1.0f / __shfl(lsumA, g * 4 + r, 64);
            invB[r] = 1.0f / __shfl(lsumB, g * 4 + r, 64);
        }
        float* outh = out + (size_t)b * SEQ * DMODEL + h * HD;
#pragma unroll
        for (int r = 0; r < 4; ++r) {
            const size_t roA = (size_t)(qbase + w * 16 + g * 4 + r) * DMODEL;
            outh[roA + 0 * 16 + n] = oA0[r] * invA[r];
            outh[roA + 1 * 16 + n] = oA1[r] * invA[r];
            outh[roA + 2 * 16 + n] = oA2[r] * invA[r];
            outh[roA + 3 * 16 + n] = oA3[r] * invA[r];
            const size_t roB = roA + (size_t)64 * DMODEL;
            outh[roB + 0 * 16 + n] = oB0[r] * invB[r];
            outh[roB + 1 * 16 + n] = oB1[r] * invB[r];
            outh[roB + 2 * 16 + n] = oB2[r] * invB[r];
            outh[roB + 3 * 16 + n] = oB3[r] * invB[r];
        }
    } else {
        const int slotP = (bh * 8 + (qtp - 8)) * 2 + half;
        float* ob = oPart + (size_t)slotP * 8192;
#pragma unroll
        for (int r = 0; r < 4; ++r) {
            const int rowA = w * 16 + g * 4 + r;
            ob[rowA * 64 + 0 * 16 + n] = oA0[r];
            ob[rowA * 64 + 1 * 16 + n] = oA1[r];
            ob[rowA * 64 + 2 * 16 + n] = oA2[r];
            ob[rowA * 64 + 3 * 16 + n] = oA3[r];
            const int rowB = rowA + 64;
            ob[rowB * 64 + 0 * 16 + n] = oB0[r];
            ob[rowB * 64 + 1 * 16 + n] = oB1[r];
            ob[rowB * 64 + 2 * 16 + n] = oB2[r];
            ob[rowB * 64 + 3 * 16 + n] = oB3[r];
        }
        if (g == 0) {
            lPart[slotP * 128 + w * 16 + n] = lsumA;
            lPart[slotP * 128 + 64 + w * 16 + n] = lsumB;
        }
    }
}

// ---------------------------------------------------------------------------
// Combine: out = (o_lo + o_hi) / (l_lo + l_hi) for split tiles qt' 8..15.
// grid 256 = BH * 8, block 256; thread owns one half-row (32 d).
// ---------------------------------------------------------------------------
__global__ __launch_bounds__(256) void combine_kernel(const float* __restrict__ oPart,
                                                      const float* __restrict__ lPart,
                                                      float* __restrict__ out) {
    const int bid = blockIdx.x;
    const int bh = bid & (BH - 1);
    const int t = bid >> 5;                    // split tile 0..7 (qt' = 8+t)
    const int b = bh >> 4, h = bh & (NHEAD - 1);
    const int tid = threadIdx.x;
    const int row = tid >> 1;                  // 0..127
    const int dq = (tid & 1) * 32;
    const int slotP = (bh * 8 + t) * 2;
    const float l = lPart[slotP * 128 + row] + lPart[(slotP + 1) * 128 + row];
    const float inv = 1.0f / l;
    const float* lo = oPart + (size_t)slotP * 8192 + row * 64 + dq;
    const float* hi = lo + 8192;
    float* op = out + ((size_t)(b * SEQ + (8 + t) * 128 + row)) * DMODEL + h * HD + dq;
#pragma unroll
    for (int i = 0; i < 8; ++i) {
        float4 a = *(const float4*)(lo + i * 4);
        float4 c = *(const float4*)(hi + i * 4);
        float4 o;
        o.x = (a.x + c.x) * inv;
        o.y = (a.y + c.y) * inv;
        o.z = (a.z + c.z) * inv;
        o.w = (a.w + c.w) * inv;
        *(float4*)(op + i * 4) = o;
    }
}

// ---------------------------------------------------------------------------
// Fallback (round-1 fp32 kernel, known-correct) if workspace is too small.
// ---------------------------------------------------------------------------
#define KT 32
#define QR 16
#define LDS_STRIDE 68

__global__ __launch_bounds__(64, 2)
void attn_fp32_kernel(const float* __restrict__ x, float* __restrict__ out) {
    __shared__ float kv[KT * LDS_STRIDE];
    const int id = blockIdx.x;
    const int bh = id & (BATCH * NHEAD - 1);
    const int qt = (SEQ / QR - 1) - (id >> 5);
    const int b = bh >> 4, h = bh & (NHEAD - 1);
    const int lane = threadIdx.x;
    const int row = lane & (QR - 1);
    const int slice = lane >> 4;
    const int qrow = qt * QR + row;
    const float* xh = x + (size_t)b * SEQ * DMODEL + (size_t)h * HD;
    float q[HD], o[HD];
    const float4* qp = (const float4*)(xh + (size_t)qrow * DMODEL);
#pragma unroll
    for (int i = 0; i < HD / 4; ++i) {
        float4 v = qp[i];
        q[4*i+0] = v.x * 0.125f; q[4*i+1] = v.y * 0.125f;
        q[4*i+2] = v.z * 0.125f; q[4*i+3] = v.w * 0.125f;
    }
#pragma unroll
    for (int d = 0; d < HD; ++d) o[d] = 0.0f;
    float l = 0.0f;
    const int kend = qt * QR + QR;
    for (int kt0 = 0; kt0 < kend; kt0 += KT) {
        __syncthreads();
#pragma unroll
        for (int i = 0; i < (KT * HD / 4) / 64; ++i) {
            int idx = i * 64 + lane;
            int r = idx >> 4, cc = idx & 15;
            *(float4*)(kv + r * LDS_STRIDE + cc * 4) =
                *(const float4*)(xh + (size_t)(kt0 + r) * DMODEL + cc * 4);
        }
        __syncthreads();
#pragma unroll 2
        for (int jj = 0; jj < KT / 4; ++jj) {
            const int j = jj * 4 + slice;
            const float* kr = kv + j * LDS_STRIDE;
            float a0 = 0.f, a1 = 0.f, a2 = 0.f, a3 = 0.f;
#pragma unroll
            for (int dq = 0; dq < 16; ++dq) {
                float4 kk = ((const float4*)kr)[dq];
                a0 = fmaf(q[4*dq+0], kk.x, a0); a1 = fmaf(q[4*dq+1], kk.y, a1);
                a2 = fmaf(q[4*dq+2], kk.z, a2); a3 = fmaf(q[4*dq+3], kk.w, a3);
            }
            float p = __expf((a0 + a1) + (a2 + a3));
            p = (kt0 + j <= qrow) ? p : 0.0f;
            l += p;
#pragma unroll
            for (int dq = 0; dq < 16; ++dq) {
                float4 vv = ((const float4*)kr)[dq];
                o[4*dq+0] = fmaf(p, vv.x, o[4*dq+0]); o[4*dq+1] = fmaf(p, vv.y, o[4*dq+1]);
                o[4*dq+2] = fmaf(p, vv.z, o[4*dq+2]); o[4*dq+3] = fmaf(p, vv.w, o[4*dq+3]);
            }
        }
    }
    l += __shfl_xor(l, 16, 64);
    l += __shfl_xor(l, 32, 64);
#pragma unroll
    for (int d = 0; d < HD; ++d) {
        o[d] += __shfl_xor(o[d], 16, 64);
        o[d] += __shfl_xor(o[d], 32, 64);
    }
    if (slice == 0) {
        const float invl = 1.0f / l;
        float4* op = (float4*)(out + ((size_t)b * SEQ + qrow) * DMODEL + (size_t)h * HD);
#pragma unroll
        for (int i = 0; i < HD / 4; ++i) {
            float4 v;
            v.x = o[4*i+0] * invl; v.y = o[4*i+1] * invl;
            v.z = o[4*i+2] * invl; v.w = o[4*i+3] * invl;
            op[i] = v;
        }
    }
}

extern "C" void kernel_launch(void* const* d_in, const int* in_sizes, int n_in,
                              void* d_out, int out_size, void* d_ws, size_t ws_size,
                              hipStream_t stream) {
    const float* x = (const float*)d_in[0];
    float* out = (float*)d_out;
    const size_t nXb = (size_t)BATCH * SEQ * DMODEL;            // u16 elems
    const size_t nOP = (size_t)BH * 8 * 2 * 8192;               // f32 elems
    const size_t nLP = (size_t)BH * 8 * 2 * 128;                // f32 elems
    const size_t need = 2 * nXb * 2 + (nOP + nLP) * 4;          // bytes
    if (ws_size >= need) {
        unsigned short* xb  = (unsigned short*)d_ws;
        unsigned short* xbT = xb + nXb;
        float* oPart = (float*)(xbT + nXb);
        float* lPart = oPart + nOP;
        hipLaunchKernelGGL(prep_kernel, dim3(BH * SEQ / 32), dim3(256), 0, stream,
                           x, xb, xbT);
        hipLaunchKernelGGL(flash_kernel, dim3(768), dim3(256), 0, stream,
                           xb, xbT, out, oPart, lPart);
        hipLaunchKernelGGL(combine_kernel, dim3(BH * 8), dim3(256), 0, stream,
                           oPart, lPart, out);
    } else {
        hipLaunchKernelGGL(attn_fp32_kernel, dim3(BATCH * NHEAD * (SEQ / QR)), dim3(64), 0,
                           stream, x, out);
    }
}

// Round 9
// 104.032 us; speedup vs baseline: 1.0963x; 1.0963x over previous
//
#include <hip/hip_runtime.h>
#include <hip/hip_bf16.h>

#define BATCH  2
#define SEQ    2048
#define DMODEL 1024
#define NHEAD  16
#define HD     64
#define BH     (BATCH * NHEAD)

typedef __attribute__((ext_vector_type(8))) short s8v;   // 8 bf16 = 4 VGPRs (MFMA A/B frag)
typedef __attribute__((ext_vector_type(4))) float f4v;   // MFMA C/D frag

// sqrt(0.125 * log2(e)): folded QK^T scale (beta^2 = 0.18033688)
#define QK_BETA 0.42466089f

__device__ inline unsigned short bf16_rne(float f) {
    unsigned u = __builtin_bit_cast(unsigned, f);
    u += 0x7FFFu + ((u >> 16) & 1u);
    return (unsigned short)(u >> 16);
}

// pack two f32 -> u32 of 2 bf16 via hardware v_cvt_pk_bf16_f32 (RNE, same
// rounding as bf16_rne bit-trick). memcpy, not bit_cast (r5: __hip_bfloat162
// is not trivially copyable on this ROCm).
__device__ __forceinline__ unsigned pk_bf16(float lo, float hi) {
    __hip_bfloat162 h = __float22bfloat162_rn(make_float2(lo, hi));
    unsigned u;
    __builtin_memcpy(&u, &h, 4);
    return u;
}

// ---------------------------------------------------------------------------
// Prep v3: x fp32 -> xb bf16 SCALED by QK_BETA (Q/K path) and xbT bf16
// UNSCALED [bh][d][s] (V path). grid 2048, block 256, 32(s) x 64(d) tile.
// ---------------------------------------------------------------------------
__global__ __launch_bounds__(256) void prep_kernel(const float* __restrict__ x,
                                                   unsigned short* __restrict__ xb,
                                                   unsigned short* __restrict__ xbT) {
    __shared__ unsigned short tile[32 * 66];   // stride 66 u16: avoids pow-2 conflicts
    const int id = blockIdx.x;
    const int bh = id & (BH - 1);
    const int st = id >> 5;                    // s-tile 0..63
    const int b = bh >> 4, h = bh & (NHEAD - 1);
    const int s0 = st * 32;
    const int tid = threadIdx.x;
    const int c4 = tid & 15, r16 = tid >> 4;

#pragma unroll
    for (int p = 0; p < 2; ++p) {
        const int sl = p * 16 + r16;
        const size_t off = (size_t)(b * SEQ + s0 + sl) * DMODEL + h * HD + c4 * 4;
        float4 v = *(const float4*)(x + off);
        ushort4 os;                             // scaled -> xb (Q/K operand)
        os.x = bf16_rne(v.x * QK_BETA); os.y = bf16_rne(v.y * QK_BETA);
        os.z = bf16_rne(v.z * QK_BETA); os.w = bf16_rne(v.w * QK_BETA);
        *(ushort4*)(xb + off) = os;
        unsigned short* t = tile + sl * 66 + c4 * 4;   // unscaled -> xbT (V)
        t[0] = bf16_rne(v.x); t[1] = bf16_rne(v.y);
        t[2] = bf16_rne(v.z); t[3] = bf16_rne(v.w);
    }
    __syncthreads();
    {
        const int d = tid >> 2;                // 0..63
        const int sb = (tid & 3) * 8;          // s-chunk 0,8,16,24
        s8v o;
#pragma unroll
        for (int j = 0; j < 8; ++j)
            o[j] = (short)tile[(sb + j) * 66 + d];
        *(s8v*)(xbT + (size_t)(bh * HD + d) * SEQ + s0 + sb) = o;
    }
}

// ---------------------------------------------------------------------------
// Stage one 64x64 K tile + 64x64 V^T tile into LDS buffer at bufoff.
// Waves 0,1: K rows (XOR-swizzled d-chunks). Waves 2,3: V^T rows (swizzled k).
// 4 x global_load_lds(16B) per wave.  [verbatim round-1, verified passing]
// ---------------------------------------------------------------------------
__device__ __forceinline__ void stage_tile(const unsigned short* __restrict__ xbh,
                                           const unsigned short* __restrict__ xTh,
                                           char* lds, int bufoff, int k0,
                                           int w, int sr, int sc) {
    if (w < 2) {
#pragma unroll
        for (int i = 0; i < 4; ++i) {
            const int r = w * 32 + i * 8 + sr;
            const unsigned short* gsrc =
                xbh + (size_t)(k0 + r) * DMODEL + ((sc ^ (r & 7)) * 8);
            const int loff = __builtin_amdgcn_readfirstlane(bufoff + (w * 32 + i * 8) * 128);
            __builtin_amdgcn_global_load_lds(
                (const __attribute__((address_space(1))) void*)gsrc,
                (__attribute__((address_space(3))) void*)(lds + loff), 16, 0, 0);
        }
    } else {
#pragma unroll
        for (int i = 0; i < 4; ++i) {
            const int d = (w - 2) * 32 + i * 8 + sr;
            const unsigned short* gsrc =
                xTh + (size_t)d * SEQ + k0 + ((sc ^ (d & 7)) * 8);
            const int loff =
                __builtin_amdgcn_readfirstlane(bufoff + 8192 + ((w - 2) * 32 + i * 8) * 128);
            __builtin_amdgcn_global_load_lds(
                (const __attribute__((address_space(1))) void*)gsrc,
                (__attribute__((address_space(3))) void*)(lds + loff), 16, 0, 0);
        }
    }
}

// ---------------------------------------------------------------------------
// Flash attention, bf16 MFMA 16x16x32, swapped QK^T (round-6 skeleton —
// verified passing; r7/r8 partial/combine machinery reverted: zero flash gain
// for ~7us extra HBM). VALU-reduction round:
//  - scale folded into xb (no per-element mul)
//  - v_cvt_pk_bf16_f32 pack (1 op/pair vs ~10)
//  - l-sum via MFMA with ones-B: lacc[r] lands in exactly the lane/row that
//    writes q = g*4+r -> no epilogue shuffles at all.
// ---------------------------------------------------------------------------
__global__ __launch_bounds__(256, 4) void flash_kernel(const unsigned short* __restrict__ xb,
                                                       const unsigned short* __restrict__ xbT,
                                                       float* __restrict__ out) {
    __shared__ __align__(16) char lds[40960];

    const int id = blockIdx.x;
    const int bh = id & (BH - 1);
    const int t5 = id >> 5;                    // 0..31
    const int rr = t5 >> 3, uu = t5 & 7;
    // balanced + roughly longest-first: per-u qt sums to 62 over rr=0..3
    const int qt = (rr == 0) ? (31 - uu) : (rr == 1) ? (16 + uu)
                 : (rr == 2) ? (15 - uu) : uu;
    const int b = bh >> 4, h = bh & (NHEAD - 1);
    const int tid = threadIdx.x;
    const int w = tid >> 6;                            // wave 0..3
    const int lane = tid & 63;
    const int n = lane & 15;                           // MFMA m/n index
    const int g = lane >> 4;                           // MFMA quad
    const int qbase = qt * 64;

    const unsigned short* xbh = xb + (size_t)b * SEQ * DMODEL + h * HD;
    const unsigned short* xTh = xbT + (size_t)bh * HD * SEQ;

    // Q fragments (B-operand in swapped QK^T: n=q-row, k-chunk=quad)
    const int qrow = qbase + w * 16 + n;
    const s8v qf0 = *(const s8v*)(xbh + (size_t)qrow * DMODEL + g * 8);
    const s8v qf1 = *(const s8v*)(xbh + (size_t)qrow * DMODEL + 32 + g * 8);

    // ones B-frag (bf16 1.0 = 0x3F80) for the l-sum MFMA
    s8v ones;
#pragma unroll
    for (int j = 0; j < 8; ++j) ones[j] = (short)0x3F80;

    // B-frag LDS byte offsets (same formula for kRow & kCol): row t*16+n,
    // chunk c at XOR-swizzled slot (c ^ (row&7)); row&7 == n&7.
    int roff0[4], roff1[4];
#pragma unroll
    for (int t = 0; t < 4; ++t) {
        roff0[t] = (t * 16 + n) * 128 + ((g ^ (n & 7)) * 16);
        roff1[t] = (t * 16 + n) * 128 + (((4 + g) ^ (n & 7)) * 16);
    }

    f4v o0 = {0.f, 0.f, 0.f, 0.f}, o1 = o0, o2 = o0, o3 = o0;
    f4v lacc = o0;
    char* const Pbase = lds + 32768 + w * 2048;

    // P-scratch write addrs (loop-invariant): pair (k=16t+4g+{0,1},{2,3})
    char* wrP[4];
#pragma unroll
    for (int t = 0; t < 4; ++t)
        wrP[t] = Pbase + (t >> 1) * 1024 + n * 64 +
                 ((((t & 1) * 2 + (g >> 1)) ^ (n & 3)) * 16) + (g & 1) * 8;
    // P-scratch read addrs: q=n, kw-quad g (pa0) swizzled by n&3
    const char* rdP = Pbase + n * 64 + ((g ^ (n & 3)) * 16);

    const int sr = lane >> 3;   // staging: row within 8-row chunk
    const int sc = lane & 7;    // staging: 16B slot within row

    // prologue: prefetch tile 0 into buf0
    stage_tile(xbh, xTh, lds, 0, 0, w, sr, sc);

    for (int kt = 0; kt <= qt; ++kt) {
        char* const buf = lds + ((kt & 1) << 14);
        // Drains only this tile's own 4 loads (issued a full iteration ago);
        // also guarantees every wave finished reading buf^1, so restaging it
        // below is race-free.
        __syncthreads();
        if (kt < qt)
            stage_tile(xbh, xTh, lds, ((kt & 1) ^ 1) << 14, (kt + 1) * 64, w, sr, sc);

        const bool diag = (kt == qt);
        // ---- QK^T (swapped: A=K, B=Q; pre-scaled operands) + packed P ----
#pragma unroll
        for (int t = 0; t < 4; ++t) {
            const s8v kb0 = *(const s8v*)(buf + roff0[t]);
            const s8v kb1 = *(const s8v*)(buf + roff1[t]);
            f4v c = {0.f, 0.f, 0.f, 0.f};
            __builtin_amdgcn_s_setprio(1);
            c = __builtin_amdgcn_mfma_f32_16x16x32_bf16(kb0, qf0, c, 0, 0, 0);
            c = __builtin_amdgcn_mfma_f32_16x16x32_bf16(kb1, qf1, c, 0, 0, 0);
            __builtin_amdgcn_s_setprio(0);
            // lane holds S[k = t*16+g*4+r][q = w*16+n], already x log2(e)/8
            float p0 = __builtin_amdgcn_exp2f(c[0]);
            float p1 = __builtin_amdgcn_exp2f(c[1]);
            float p2 = __builtin_amdgcn_exp2f(c[2]);
            float p3 = __builtin_amdgcn_exp2f(c[3]);
            if (diag) {    // wave-uniform branch: mask only on the diag tile
                const int kl = t * 16 + g * 4, ql = w * 16 + n;
                p0 = (kl + 0 <= ql) ? p0 : 0.0f;
                p1 = (kl + 1 <= ql) ? p1 : 0.0f;
                p2 = (kl + 2 <= ql) ? p2 : 0.0f;
                p3 = (kl + 3 <= ql) ? p3 : 0.0f;
            }
            uint2 u;
            u.x = pk_bf16(p0, p1);
            u.y = pk_bf16(p2, p3);
            *(uint2*)(wrP[t]) = u;   // ds_write_b64
        }

        // ---- PV: A = P (per-wave scratch, b128), B = V^T; + l via ones ----
        const s8v pa0 = *(const s8v*)(rdP);
        const s8v pa1 = *(const s8v*)(rdP + 1024);
        const char* kColB = buf + 8192;
        {
            s8v vb;
            __builtin_amdgcn_s_setprio(1);
            lacc = __builtin_amdgcn_mfma_f32_16x16x32_bf16(pa0, ones, lacc, 0, 0, 0);
            vb = *(const s8v*)(kColB + roff0[0]);
            o0 = __builtin_amdgcn_mfma_f32_16x16x32_bf16(pa0, vb, o0, 0, 0, 0);
            vb = *(const s8v*)(kColB + roff1[0]);
            o0 = __builtin_amdgcn_mfma_f32_16x16x32_bf16(pa1, vb, o0, 0, 0, 0);
            vb = *(const s8v*)(kColB + roff0[1]);
            o1 = __builtin_amdgcn_mfma_f32_16x16x32_bf16(pa0, vb, o1, 0, 0, 0);
            vb = *(const s8v*)(kColB + roff1[1]);
            o1 = __builtin_amdgcn_mfma_f32_16x16x32_bf16(pa1, vb, o1, 0, 0, 0);
            lacc = __builtin_amdgcn_mfma_f32_16x16x32_bf16(pa1, ones, lacc, 0, 0, 0);
            vb = *(const s8v*)(kColB + roff0[2]);
            o2 = __builtin_amdgcn_mfma_f32_16x16x32_bf16(pa0, vb, o2, 0, 0, 0);
            vb = *(const s8v*)(kColB + roff1[2]);
            o2 = __builtin_amdgcn_mfma_f32_16x16x32_bf16(pa1, vb, o2, 0, 0, 0);
            vb = *(const s8v*)(kColB + roff0[3]);
            o3 = __builtin_amdgcn_mfma_f32_16x16x32_bf16(pa0, vb, o3, 0, 0, 0);
            vb = *(const s8v*)(kColB + roff1[3]);
            o3 = __builtin_amdgcn_mfma_f32_16x16x32_bf16(pa1, vb, o3, 0, 0, 0);
            __builtin_amdgcn_s_setprio(0);
        }
    }

    // ---- epilogue: lacc[r] = l[q = g*4+r] already lane-resident ----
    f4v inv;
#pragma unroll
    for (int r = 0; r < 4; ++r)
        inv[r] = 1.0f / lacc[r];

    float* outh = out + (size_t)b * SEQ * DMODEL + h * HD;
#pragma unroll
    for (int r = 0; r < 4; ++r) {
        const size_t rowoff = (size_t)(qbase + w * 16 + g * 4 + r) * DMODEL;
        outh[rowoff + 0 * 16 + n] = o0[r] * inv[r];
        outh[rowoff + 1 * 16 + n] = o1[r] * inv[r];
        outh[rowoff + 2 * 16 + n] = o2[r] * inv[r];
        outh[rowoff + 3 * 16 + n] = o3[r] * inv[r];
    }
}

// ---------------------------------------------------------------------------
// Fallback (round-1 fp32 kernel, known-correct) if workspace is too small.
// ---------------------------------------------------------------------------
#define KT 32
#define QR 16
#define LDS_STRIDE 68

__global__ __launch_bounds__(64, 2)
void attn_fp32_kernel(const float* __restrict__ x, float* __restrict__ out) {
    __shared__ float kv[KT * LDS_STRIDE];
    const int id = blockIdx.x;
    const int bh = id & (BATCH * NHEAD - 1);
    const int qt = (SEQ / QR - 1) - (id >> 5);
    const int b = bh >> 4, h = bh & (NHEAD - 1);
    const int lane = threadIdx.x;
    const int row = lane & (QR - 1);
    const int slice = lane >> 4;
    const int qrow = qt * QR + row;
    const float* xh = x + (size_t)b * SEQ * DMODEL + (size_t)h * HD;
    float q[HD], o[HD];
    const float4* qp = (const float4*)(xh + (size_t)qrow * DMODEL);
#pragma unroll
    for (int i = 0; i < HD / 4; ++i) {
        float4 v = qp[i];
        q[4*i+0] = v.x * 0.125f; q[4*i+1] = v.y * 0.125f;
        q[4*i+2] = v.z * 0.125f; q[4*i+3] = v.w * 0.125f;
    }
#pragma unroll
    for (int d = 0; d < HD; ++d) o[d] = 0.0f;
    float l = 0.0f;
    const int kend = qt * QR + QR;
    for (int kt0 = 0; kt0 < kend; kt0 += KT) {
        __syncthreads();
#pragma unroll
        for (int i = 0; i < (KT * HD / 4) / 64; ++i) {
            int idx = i * 64 + lane;
            int r = idx >> 4, cc = idx & 15;
            *(float4*)(kv + r * LDS_STRIDE + cc * 4) =
                *(const float4*)(xh + (size_t)(kt0 + r) * DMODEL + cc * 4);
        }
        __syncthreads();
#pragma unroll 2
        for (int jj = 0; jj < KT / 4; ++jj) {
            const int j = jj * 4 + slice;
            const float* kr = kv + j * LDS_STRIDE;
            float a0 = 0.f, a1 = 0.f, a2 = 0.f, a3 = 0.f;
#pragma unroll
            for (int dq = 0; dq < 16; ++dq) {
                float4 kk = ((const float4*)kr)[dq];
                a0 = fmaf(q[4*dq+0], kk.x, a0); a1 = fmaf(q[4*dq+1], kk.y, a1);
                a2 = fmaf(q[4*dq+2], kk.z, a2); a3 = fmaf(q[4*dq+3], kk.w, a3);
            }
            float p = __expf((a0 + a1) + (a2 + a3));
            p = (kt0 + j <= qrow) ? p : 0.0f;
            l += p;
#pragma unroll
            for (int dq = 0; dq < 16; ++dq) {
                float4 vv = ((const float4*)kr)[dq];
                o[4*dq+0] = fmaf(p, vv.x, o[4*dq+0]); o[4*dq+1] = fmaf(p, vv.y, o[4*dq+1]);
                o[4*dq+2] = fmaf(p, vv.z, o[4*dq+2]); o[4*dq+3] = fmaf(p, vv.w, o[4*dq+3]);
            }
        }
    }
    l += __shfl_xor(l, 16, 64);
    l += __shfl_xor(l, 32, 64);
#pragma unroll
    for (int d = 0; d < HD; ++d) {
        o[d] += __shfl_xor(o[d], 16, 64);
        o[d] += __shfl_xor(o[d], 32, 64);
    }
    if (slice == 0) {
        const float invl = 1.0f / l;
        float4* op = (float4*)(out + ((size_t)b * SEQ + qrow) * DMODEL + (size_t)h * HD);
#pragma unroll
        for (int i = 0; i < HD / 4; ++i) {
            float4 v;
            v.x = o[4*i+0] * invl; v.y = o[4*i+1] * invl;
            v.z = o[4*i+2] * invl; v.w = o[4*i+3] * invl;
            op[i] = v;
        }
    }
}

extern "C" void kernel_launch(void* const* d_in, const int* in_sizes, int n_in,
                              void* d_out, int out_size, void* d_ws, size_t ws_size,
                              hipStream_t stream) {
    const float* x = (const float*)d_in[0];
    float* out = (float*)d_out;
    const size_t nXb = (size_t)BATCH * SEQ * DMODEL;            // u16 elems
    const size_t need = 2 * nXb * 2;                            // xb + xbT
    if (ws_size >= need) {
        unsigned short* xb  = (unsigned short*)d_ws;
        unsigned short* xbT = xb + nXb;
        hipLaunchKernelGGL(prep_kernel, dim3(BH * SEQ / 32), dim3(256), 0, stream,
                           x, xb, xbT);
        hipLaunchKernelGGL(flash_kernel, dim3(BH * SEQ / 64), dim3(256), 0, stream,
                           xb, xbT, out);
    } else {
        hipLaunchKernelGGL(attn_fp32_kernel, dim3(BATCH * NHEAD * (SEQ / QR)), dim3(64), 0,
                           stream, x, out);
    }
}

// Round 11
// 103.656 us; speedup vs baseline: 1.1002x; 1.0036x over previous
//
#include <hip/hip_runtime.h>
#include <hip/hip_bf16.h>

#define BATCH  2
#define SEQ    2048
#define DMODEL 1024
#define NHEAD  16
#define HD     64
#define BH     (BATCH * NHEAD)

typedef __attribute__((ext_vector_type(8))) short s8v;   // 8 bf16 = 4 VGPRs (MFMA A/B frag)
typedef __attribute__((ext_vector_type(4))) float f4v;   // MFMA C/D frag

// sqrt(0.125 * log2(e)): folded QK^T scale (beta^2 = 0.18033688)
#define QK_BETA 0.42466089f

__device__ inline unsigned short bf16_rne(float f) {
    unsigned u = __builtin_bit_cast(unsigned, f);
    u += 0x7FFFu + ((u >> 16) & 1u);
    return (unsigned short)(u >> 16);
}

// pack two f32 -> u32 of 2 bf16 via hardware v_cvt_pk_bf16_f32 (RNE, same
// rounding as bf16_rne bit-trick). memcpy, not bit_cast (r5: __hip_bfloat162
// is not trivially copyable on this ROCm).
__device__ __forceinline__ unsigned pk_bf16(float lo, float hi) {
    __hip_bfloat162 h = __float22bfloat162_rn(make_float2(lo, hi));
    unsigned u;
    __builtin_memcpy(&u, &h, 4);
    return u;
}

// ---------------------------------------------------------------------------
// Prep v4: x fp32 -> xb bf16 SCALED by QK_BETA (Q/K path) and xbT bf16
// UNSCALED [bh][d][s] (V path). grid 2048, block 256, 32(s) x 64(d) tile.
// v3's phase-2 did 8 scalar ds_read_u16/thread (3x off roofline); v4 stores
// the tile TRANSPOSED in phase 1 (same scalar-write count) so phase 2 is one
// ds_read_b128 + one 16B store. Output bytes bit-identical to v3.
// ---------------------------------------------------------------------------
__global__ __launch_bounds__(256) void prep_kernel(const float* __restrict__ x,
                                                   unsigned short* __restrict__ xb,
                                                   unsigned short* __restrict__ xbT) {
    // tileT[d][s]: d = 0..63 rows, s = 0..31; stride 40 u16 = 80 B so that
    // byte offset d*80 + 2*s is 16B-aligned for s in {0,8,16,24}.
    __shared__ unsigned short tileT[64 * 40];
    const int id = blockIdx.x;
    const int bh = id & (BH - 1);
    const int st = id >> 5;                    // s-tile 0..63
    const int b = bh >> 4, h = bh & (NHEAD - 1);
    const int s0 = st * 32;
    const int tid = threadIdx.x;
    const int c4 = tid & 15, r16 = tid >> 4;

    // issue both global loads up front (ILP), then convert/store
    const size_t off0 = (size_t)(b * SEQ + s0 + r16) * DMODEL + h * HD + c4 * 4;
    const size_t off1 = (size_t)(b * SEQ + s0 + 16 + r16) * DMODEL + h * HD + c4 * 4;
    const float4 v0 = *(const float4*)(x + off0);
    const float4 v1 = *(const float4*)(x + off1);

    {   // scaled -> xb (Q/K operand), 8B per p via hardware cvt_pk
        uint2 u;
        u.x = pk_bf16(v0.x * QK_BETA, v0.y * QK_BETA);
        u.y = pk_bf16(v0.z * QK_BETA, v0.w * QK_BETA);
        *(uint2*)(xb + off0) = u;
        u.x = pk_bf16(v1.x * QK_BETA, v1.y * QK_BETA);
        u.y = pk_bf16(v1.z * QK_BETA, v1.w * QK_BETA);
        *(uint2*)(xb + off1) = u;
    }
    {   // unscaled -> tileT (transposed store: 4 scalar u16 per p-iter)
        const int d0 = c4 * 4;
        unsigned short* t0 = tileT + r16;          // column s = r16
        t0[(d0 + 0) * 40] = bf16_rne(v0.x);
        t0[(d0 + 1) * 40] = bf16_rne(v0.y);
        t0[(d0 + 2) * 40] = bf16_rne(v0.z);
        t0[(d0 + 3) * 40] = bf16_rne(v0.w);
        unsigned short* t1 = tileT + 16 + r16;     // column s = 16 + r16
        t1[(d0 + 0) * 40] = bf16_rne(v1.x);
        t1[(d0 + 1) * 40] = bf16_rne(v1.y);
        t1[(d0 + 2) * 40] = bf16_rne(v1.z);
        t1[(d0 + 3) * 40] = bf16_rne(v1.w);
    }
    __syncthreads();
    {   // phase 2: one b128 LDS read + one 16B global store per thread
        const int d = tid >> 2;                // 0..63
        const int sq = (tid & 3) * 8;          // s-chunk 0,8,16,24
        const s8v o = *(const s8v*)(tileT + d * 40 + sq);
        *(s8v*)(xbT + (size_t)(bh * HD + d) * SEQ + s0 + sq) = o;
    }
}

// ---------------------------------------------------------------------------
// Stage one 64x64 K tile + 64x64 V^T tile into LDS buffer at bufoff.
// Waves 0,1: K rows (XOR-swizzled d-chunks). Waves 2,3: V^T rows (swizzled k).
// 4 x global_load_lds(16B) per wave.  [verbatim round-1, verified passing]
// ---------------------------------------------------------------------------
__device__ __forceinline__ void stage_tile(const unsigned short* __restrict__ xbh,
                                           const unsigned short* __restrict__ xTh,
                                           char* lds, int bufoff, int k0,
                                           int w, int sr, int sc) {
    if (w < 2) {
#pragma unroll
        for (int i = 0; i < 4; ++i) {
            const int r = w * 32 + i * 8 + sr;
            const unsigned short* gsrc =
                xbh + (size_t)(k0 + r) * DMODEL + ((sc ^ (r & 7)) * 8);
            const int loff = __builtin_amdgcn_readfirstlane(bufoff + (w * 32 + i * 8) * 128);
            __builtin_amdgcn_global_load_lds(
                (const __attribute__((address_space(1))) void*)gsrc,
                (__attribute__((address_space(3))) void*)(lds + loff), 16, 0, 0);
        }
    } else {
#pragma unroll
        for (int i = 0; i < 4; ++i) {
            const int d = (w - 2) * 32 + i * 8 + sr;
            const unsigned short* gsrc =
                xTh + (size_t)d * SEQ + k0 + ((sc ^ (d & 7)) * 8);
            const int loff =
                __builtin_amdgcn_readfirstlane(bufoff + 8192 + ((w - 2) * 32 + i * 8) * 128);
            __builtin_amdgcn_global_load_lds(
                (const __attribute__((address_space(1))) void*)gsrc,
                (__attribute__((address_space(3))) void*)(lds + loff), 16, 0, 0);
        }
    }
}

// ---------------------------------------------------------------------------
// Flash attention, bf16 MFMA 16x16x32, swapped QK^T.
// [verbatim round-9 kernel — verified passing at 104.0 us total]
// ---------------------------------------------------------------------------
__global__ __launch_bounds__(256, 4) void flash_kernel(const unsigned short* __restrict__ xb,
                                                       const unsigned short* __restrict__ xbT,
                                                       float* __restrict__ out) {
    __shared__ __align__(16) char lds[40960];

    const int id = blockIdx.x;
    const int bh = id & (BH - 1);
    const int t5 = id >> 5;                    // 0..31
    const int rr = t5 >> 3, uu = t5 & 7;
    // balanced + roughly longest-first: per-u qt sums to 62 over rr=0..3
    const int qt = (rr == 0) ? (31 - uu) : (rr == 1) ? (16 + uu)
                 : (rr == 2) ? (15 - uu) : uu;
    const int b = bh >> 4, h = bh & (NHEAD - 1);
    const int tid = threadIdx.x;
    const int w = tid >> 6;                            // wave 0..3
    const int lane = tid & 63;
    const int n = lane & 15;                           // MFMA m/n index
    const int g = lane >> 4;                           // MFMA quad
    const int qbase = qt * 64;

    const unsigned short* xbh = xb + (size_t)b * SEQ * DMODEL + h * HD;
    const unsigned short* xTh = xbT + (size_t)bh * HD * SEQ;

    // Q fragments (B-operand in swapped QK^T: n=q-row, k-chunk=quad)
    const int qrow = qbase + w * 16 + n;
    const s8v qf0 = *(const s8v*)(xbh + (size_t)qrow * DMODEL + g * 8);
    const s8v qf1 = *(const s8v*)(xbh + (size_t)qrow * DMODEL + 32 + g * 8);

    // ones B-frag (bf16 1.0 = 0x3F80) for the l-sum MFMA
    s8v ones;
#pragma unroll
    for (int j = 0; j < 8; ++j) ones[j] = (short)0x3F80;

    // B-frag LDS byte offsets (same formula for kRow & kCol): row t*16+n,
    // chunk c at XOR-swizzled slot (c ^ (row&7)); row&7 == n&7.
    int roff0[4], roff1[4];
#pragma unroll
    for (int t = 0; t < 4; ++t) {
        roff0[t] = (t * 16 + n) * 128 + ((g ^ (n & 7)) * 16);
        roff1[t] = (t * 16 + n) * 128 + (((4 + g) ^ (n & 7)) * 16);
    }

    f4v o0 = {0.f, 0.f, 0.f, 0.f}, o1 = o0, o2 = o0, o3 = o0;
    f4v lacc = o0;
    char* const Pbase = lds + 32768 + w * 2048;

    // P-scratch write addrs (loop-invariant): pair (k=16t+4g+{0,1},{2,3})
    char* wrP[4];
#pragma unroll
    for (int t = 0; t < 4; ++t)
        wrP[t] = Pbase + (t >> 1) * 1024 + n * 64 +
                 ((((t & 1) * 2 + (g >> 1)) ^ (n & 3)) * 16) + (g & 1) * 8;
    // P-scratch read addrs: q=n, kw-quad g (pa0) swizzled by n&3
    const char* rdP = Pbase + n * 64 + ((g ^ (n & 3)) * 16);

    const int sr = lane >> 3;   // staging: row within 8-row chunk
    const int sc = lane & 7;    // staging: 16B slot within row

    // prologue: prefetch tile 0 into buf0
    stage_tile(xbh, xTh, lds, 0, 0, w, sr, sc);

    for (int kt = 0; kt <= qt; ++kt) {
        char* const buf = lds + ((kt & 1) << 14);
        // Drains only this tile's own 4 loads (issued a full iteration ago);
        // also guarantees every wave finished reading buf^1, so restaging it
        // below is race-free.
        __syncthreads();
        if (kt < qt)
            stage_tile(xbh, xTh, lds, ((kt & 1) ^ 1) << 14, (kt + 1) * 64, w, sr, sc);

        const bool diag = (kt == qt);
        // ---- QK^T (swapped: A=K, B=Q; pre-scaled operands) + packed P ----
#pragma unroll
        for (int t = 0; t < 4; ++t) {
            const s8v kb0 = *(const s8v*)(buf + roff0[t]);
            const s8v kb1 = *(const s8v*)(buf + roff1[t]);
            f4v c = {0.f, 0.f, 0.f, 0.f};
            __builtin_amdgcn_s_setprio(1);
            c = __builtin_amdgcn_mfma_f32_16x16x32_bf16(kb0, qf0, c, 0, 0, 0);
            c = __builtin_amdgcn_mfma_f32_16x16x32_bf16(kb1, qf1, c, 0, 0, 0);
            __builtin_amdgcn_s_setprio(0);
            // lane holds S[k = t*16+g*4+r][q = w*16+n], already x log2(e)/8
            float p0 = __builtin_amdgcn_exp2f(c[0]);
            float p1 = __builtin_amdgcn_exp2f(c[1]);
            float p2 = __builtin_amdgcn_exp2f(c[2]);
            float p3 = __builtin_amdgcn_exp2f(c[3]);
            if (diag) {    // wave-uniform branch: mask only on the diag tile
                const int kl = t * 16 + g * 4, ql = w * 16 + n;
                p0 = (kl + 0 <= ql) ? p0 : 0.0f;
                p1 = (kl + 1 <= ql) ? p1 : 0.0f;
                p2 = (kl + 2 <= ql) ? p2 : 0.0f;
                p3 = (kl + 3 <= ql) ? p3 : 0.0f;
            }
            uint2 u;
            u.x = pk_bf16(p0, p1);
            u.y = pk_bf16(p2, p3);
            *(uint2*)(wrP[t]) = u;   // ds_write_b64
        }

        // ---- PV: A = P (per-wave scratch, b128), B = V^T; + l via ones ----
        const s8v pa0 = *(const s8v*)(rdP);
        const s8v pa1 = *(const s8v*)(rdP + 1024);
        const char* kColB = buf + 8192;
        {
            s8v vb;
            __builtin_amdgcn_s_setprio(1);
            lacc = __builtin_amdgcn_mfma_f32_16x16x32_bf16(pa0, ones, lacc, 0, 0, 0);
            vb = *(const s8v*)(kColB + roff0[0]);
            o0 = __builtin_amdgcn_mfma_f32_16x16x32_bf16(pa0, vb, o0, 0, 0, 0);
            vb = *(const s8v*)(kColB + roff1[0]);
            o0 = __builtin_amdgcn_mfma_f32_16x16x32_bf16(pa1, vb, o0, 0, 0, 0);
            vb = *(const s8v*)(kColB + roff0[1]);
            o1 = __builtin_amdgcn_mfma_f32_16x16x32_bf16(pa0, vb, o1, 0, 0, 0);
            vb = *(const s8v*)(kColB + roff1[1]);
            o1 = __builtin_amdgcn_mfma_f32_16x16x32_bf16(pa1, vb, o1, 0, 0, 0);
            lacc = __builtin_amdgcn_mfma_f32_16x16x32_bf16(pa1, ones, lacc, 0, 0, 0);
            vb = *(const s8v*)(kColB + roff0[2]);
            o2 = __builtin_amdgcn_mfma_f32_16x16x32_bf16(pa0, vb, o2, 0, 0, 0);
            vb = *(const s8v*)(kColB + roff1[2]);
            o2 = __builtin_amdgcn_mfma_f32_16x16x32_bf16(pa1, vb, o2, 0, 0, 0);
            vb = *(const s8v*)(kColB + roff0[3]);
            o3 = __builtin_amdgcn_mfma_f32_16x16x32_bf16(pa0, vb, o3, 0, 0, 0);
            vb = *(const s8v*)(kColB + roff1[3]);
            o3 = __builtin_amdgcn_mfma_f32_16x16x32_bf16(pa1, vb, o3, 0, 0, 0);
            __builtin_amdgcn_s_setprio(0);
        }
    }

    // ---- epilogue: lacc[r] = l[q = g*4+r] already lane-resident ----
    f4v inv;
#pragma unroll
    for (int r = 0; r < 4; ++r)
        inv[r] = 1.0f / lacc[r];

    float* outh = out + (size_t)b * SEQ * DMODEL + h * HD;
#pragma unroll
    for (int r = 0; r < 4; ++r) {
        const size_t rowoff = (size_t)(qbase + w * 16 + g * 4 + r) * DMODEL;
        outh[rowoff + 0 * 16 + n] = o0[r] * inv[r];
        outh[rowoff + 1 * 16 + n] = o1[r] * inv[r];
        outh[rowoff + 2 * 16 + n] = o2[r] * inv[r];
        outh[rowoff + 3 * 16 + n] = o3[r] * inv[r];
    }
}

// ---------------------------------------------------------------------------
// Fallback (round-1 fp32 kernel, known-correct) if workspace is too small.
// ---------------------------------------------------------------------------
#define KT 32
#define QR 16
#define LDS_STRIDE 68

__global__ __launch_bounds__(64, 2)
void attn_fp32_kernel(const float* __restrict__ x, float* __restrict__ out) {
    __shared__ float kv[KT * LDS_STRIDE];
    const int id = blockIdx.x;
    const int bh = id & (BATCH * NHEAD - 1);
    const int qt = (SEQ / QR - 1) - (id >> 5);
    const int b = bh >> 4, h = bh & (NHEAD - 1);
    const int lane = threadIdx.x;
    const int row = lane & (QR - 1);
    const int slice = lane >> 4;
    const int qrow = qt * QR + row;
    const float* xh = x + (size_t)b * SEQ * DMODEL + (size_t)h * HD;
    float q[HD], o[HD];
    const float4* qp = (const float4*)(xh + (size_t)qrow * DMODEL);
#pragma unroll
    for (int i = 0; i < HD / 4; ++i) {
        float4 v = qp[i];
        q[4*i+0] = v.x * 0.125f; q[4*i+1] = v.y * 0.125f;
        q[4*i+2] = v.z * 0.125f; q[4*i+3] = v.w * 0.125f;
    }
#pragma unroll
    for (int d = 0; d < HD; ++d) o[d] = 0.0f;
    float l = 0.0f;
    const int kend = qt * QR + QR;
    for (int kt0 = 0; kt0 < kend; kt0 += KT) {
        __syncthreads();
#pragma unroll
        for (int i = 0; i < (KT * HD / 4) / 64; ++i) {
            int idx = i * 64 + lane;
            int r = idx >> 4, cc = idx & 15;
            *(float4*)(kv + r * LDS_STRIDE + cc * 4) =
                *(const float4*)(xh + (size_t)(kt0 + r) * DMODEL + cc * 4);
        }
        __syncthreads();
#pragma unroll 2
        for (int jj = 0; jj < KT / 4; ++jj) {
            const int j = jj * 4 + slice;
            const float* kr = kv + j * LDS_STRIDE;
            float a0 = 0.f, a1 = 0.f, a2 = 0.f, a3 = 0.f;
#pragma unroll
            for (int dq = 0; dq < 16; ++dq) {
                float4 kk = ((const float4*)kr)[dq];
                a0 = fmaf(q[4*dq+0], kk.x, a0); a1 = fmaf(q[4*dq+1], kk.y, a1);
                a2 = fmaf(q[4*dq+2], kk.z, a2); a3 = fmaf(q[4*dq+3], kk.w, a3);
            }
            float p = __expf((a0 + a1) + (a2 + a3));
            p = (kt0 + j <= qrow) ? p : 0.0f;
            l += p;
#pragma unroll
            for (int dq = 0; dq < 16; ++dq) {
                float4 vv = ((const float4*)kr)[dq];
                o[4*dq+0] = fmaf(p, vv.x, o[4*dq+0]); o[4*dq+1] = fmaf(p, vv.y, o[4*dq+1]);
                o[4*dq+2] = fmaf(p, vv.z, o[4*dq+2]); o[4*dq+3] = fmaf(p, vv.w, o[4*dq+3]);
            }
        }
    }
    l += __shfl_xor(l, 16, 64);
    l += __shfl_xor(l, 32, 64);
#pragma unroll
    for (int d = 0; d < HD; ++d) {
        o[d] += __shfl_xor(o[d], 16, 64);
        o[d] += __shfl_xor(o[d], 32, 64);
    }
    if (slice == 0) {
        const float invl = 1.0f / l;
        float4* op = (float4*)(out + ((size_t)b * SEQ + qrow) * DMODEL + (size_t)h * HD);
#pragma unroll
        for (int i = 0; i < HD / 4; ++i) {
            float4 v;
            v.x = o[4*i+0] * invl; v.y = o[4*i+1] * invl;
            v.z = o[4*i+2] * invl; v.w = o[4*i+3] * invl;
            op[i] = v;
        }
    }
}

extern "C" void kernel_launch(void* const* d_in, const int* in_sizes, int n_in,
                              void* d_out, int out_size, void* d_ws, size_t ws_size,
                              hipStream_t stream) {
    const float* x = (const float*)d_in[0];
    float* out = (float*)d_out;
    const size_t nXb = (size_t)BATCH * SEQ * DMODEL;            // u16 elems
    const size_t need = 2 * nXb * 2;                            // xb + xbT
    if (ws_size >= need) {
        unsigned short* xb  = (unsigned short*)d_ws;
        unsigned short* xbT = xb + nXb;
        hipLaunchKernelGGL(prep_kernel, dim3(BH * SEQ / 32), dim3(256), 0, stream,
                           x, xb, xbT);
        hipLaunchKernelGGL(flash_kernel, dim3(BH * SEQ / 64), dim3(256), 0, stream,
                           xb, xbT, out);
    } else {
        hipLaunchKernelGGL(attn_fp32_kernel, dim3(BATCH * NHEAD * (SEQ / QR)), dim3(64), 0,
                           stream, x, out);
    }
}